// Round 7
// baseline (442.326 us; speedup 1.0000x reference)
//
#include <hip/hip_runtime.h>

#define BB 16
#define LL 512
#define DD 768
#define NHEAD 12
#define HALF 256      // L/2
#define KPRES 384
#define RCNT 128      // L - K
#define UDIM 384
#define NH2 6
#define HD 64

// ---- module-scope scratch (deterministic, no atomics) ----------------------
__device__ float              g_colsum_part[BB * NHEAD * 4 * LL]; // 1.57 MB
__device__ unsigned long long g_nodep_part[BB * HALF * 4];        // 128 KB
__device__ int g_unm[BB * RCNT];
__device__ int g_srctok[BB * RCNT];
__device__ int g_srcdst[BB * RCNT];
__device__ int g_unp[BB * RCNT];
__device__ float g_q[BB * UDIM];        // q per (b, h*64+u)
__device__ float g_w2[BB * NH2 * DD];   // W2[b][h][d] = Wk_h[d,:] . q_h
__device__ float g_qbk[BB * NH2];       // q_h . bk_h
__device__ float g_ctx[BB * UDIM];      // ctx per (b, h*64+u)

// LDS overlay offsets (bytes) for k_main
#define OFF_AS   0            // sim: As dbuf [2][64][36] f32 = 18432 B  (cand aliases after loop)
#define OFF_BS   18432        // sim: BsT dbuf [2][32][68] f32 = 17408 B
#define OFF_NA   35840        // sim: nA[64]
#define OFF_NB   36096        // sim: nB[64]
#define OFF_RED  36352        // sim norms / qproj: red[256]
#define SMEM_SZ  37376

// ---------------- K_main: sim tiles (0..255, 64x64, 4x4/thread, BK=32) ------
// ----------------         + colsum (256..1023) + q-proj (1024..1119) -------
// R6 post-mortem: sim tail is LDS-read-BW bound (2x4 tile = 3 B/FLOP).
// Back to 4x4 (2 B/FLOP, R4 compute verbatim) but with double-buffered LDS,
// ONE barrier per step (24 total vs R4's 96), prefetch 2 steps ahead.
// k = 32s+4c4+kk ascending 0..767 => bit-identical dot-product chains.
__global__ void k_main(const float* __restrict__ sc, const float* __restrict__ hs,
                       const float* __restrict__ Wq, const float* __restrict__ bq) {
    __shared__ __align__(16) char smem[SMEM_SZ];
    int blk = blockIdx.x;
    int t = threadIdx.x;

    if (blk >= 1024) {
        // ---- q projection for (b,h): 4 partials of 192, round-0 FP order ---
        float* h0q = (float*)smem;
        float* red = (float*)(smem + OFF_RED);
        int qb = blk - 1024;
        int b = qb / NH2, h = qb % NH2;
        const float* hb = hs + (size_t)b * LL * DD;
        for (int d = t; d < DD; d += 256) h0q[d] = hb[d];
        __syncthreads();
        int u = t & 63, part = t >> 6;
        float a = 0.f;
        for (int d = part * 192; d < part * 192 + 192; d++)
            a += h0q[d] * Wq[(size_t)d * UDIM + h * HD + u];
        red[t] = a;
        __syncthreads();
        if (t < HD)
            g_q[b * UDIM + h * HD + t] =
                bq[h * HD + t] + red[t] + red[t + 64] + red[t + 128] + red[t + 192];
        return;
    }

    if (blk >= 256) {
        // ---- colsum partial (b,h,128-row chunk), diag excluded, float4 ----
        float4* smc = (float4*)smem;
        int cb = blk - 256;                // 0..767
        int ic = cb & 3;
        int bh = cb >> 2;                  // b*NHEAD + h
        const float* base = sc + (size_t)bh * LL * LL;
        int i0 = ic * 128;
        int p = t >> 7;                    // row parity within chunk
        int s = t & 127;                   // float4 slot -> cols 4s..4s+3
        float4 acc = {0.f, 0.f, 0.f, 0.f};
#pragma unroll 8
        for (int i = 0; i < 64; i++) {     // ascending i within parity: fixed order
            float4 v = ((const float4*)(base + (size_t)(i0 + 2 * i + p) * LL))[s];
            acc.x += v.x; acc.y += v.y; acc.z += v.z; acc.w += v.w;
        }
#pragma unroll
        for (int c = 0; c < 4; c++) {      // subtract owned diagonals
            int cj = 4 * s + c;
            if (cj >= i0 && cj < i0 + 128 && (cj & 1) == p) {
                float d = base[(size_t)cj * LL + cj];
                if (c == 0) acc.x -= d; else if (c == 1) acc.y -= d;
                else if (c == 2) acc.z -= d; else acc.w -= d;
            }
        }
        smc[t] = acc;
        __syncthreads();
        if (t < 128) {                     // partial = evens-sum + odds-sum
            float4 e = smc[t], o = smc[t + 128];
            float4 r;
            r.x = e.x + o.x; r.y = e.y + o.y; r.z = e.z + o.z; r.w = e.w + o.w;
            ((float4*)(g_colsum_part + (size_t)cb * LL))[t] = r;
        }
        return;
    }

    // ---- sim tile + fused row-argmax (64 even-rows x 64 odd-cols) ----------
    float* AsF = (float*)smem;                     // [(buf*64+row)*36 + col]
    float* BsF = (float*)(smem + OFF_BS);          // [(buf*32+k)*68 + col]
    float* nAp = (float*)(smem + OFF_NA);
    float* nBp = (float*)(smem + OFF_NB);
    float* red = (float*)(smem + OFF_RED);
    unsigned long long* cand = (unsigned long long*)smem; // aliases As after loop

    int b = blk >> 4, it = (blk >> 2) & 3, jt = blk & 3;
    int i0 = it * 64, j0 = jt * 64;
    const float* hb = hs + (size_t)b * LL * DD;
    // norms prologue: 2 threads per row, 128 rows (R4-verbatim chain)
    {
        int rl = t >> 1, hf = t & 1;
        int grow = (rl < 64) ? 2 * (i0 + rl) : 2 * (j0 + rl - 64) + 1;
        const float4* rp = (const float4*)(hb + (size_t)grow * DD) + hf * 96;
        float4 ac = {0.f, 0.f, 0.f, 0.f};
#pragma unroll 4
        for (int q = 0; q < 96; q++) {
            float4 v = rp[q];
            ac.x += v.x * v.x; ac.y += v.y * v.y; ac.z += v.z * v.z; ac.w += v.w * v.w;
        }
        red[t] = (ac.x + ac.y) + (ac.z + ac.w);
        __syncthreads();
        if (t < 128) {
            float nrm = sqrtf(red[2 * t] + red[2 * t + 1]);
            if (t < 64) nAp[t] = nrm; else nBp[t - 64] = nrm;
        }
        __syncthreads();
    }
    int ti = t >> 4, tj = t & 15;          // rows ti*4+a, cols tj*4+c
    float acc[4][4];
#pragma unroll
    for (int a = 0; a < 4; a++)
#pragma unroll
        for (int c = 0; c < 4; c++) acc[a][c] = 0.f;
    // staging: each thread owns 2 A items + 2 B items: (row r, r+32; slot sl)
    int r0 = t >> 3, sl = t & 7;
    const float* arow0 = hb + (size_t)(2 * (i0 + r0)) * DD;
    const float* arow1 = hb + (size_t)(2 * (i0 + r0 + 32)) * DD;
    const float* brow0 = hb + (size_t)(2 * (j0 + r0) + 1) * DD;
    const float* brow1 = hb + (size_t)(2 * (j0 + r0 + 32) + 1) * DD;
    float inA0 = nAp[r0], inA1 = nAp[r0 + 32];
    float inB0 = nBp[r0], inB1 = nBp[r0 + 32];
    float4 pa0, pa1, pb0, pb1;
#define LOADDIV(S)                                                              \
    do {                                                                        \
        int idx = 8 * (S) + sl;                                                 \
        pa0 = ((const float4*)arow0)[idx];                                      \
        pa1 = ((const float4*)arow1)[idx];                                      \
        pb0 = ((const float4*)brow0)[idx];                                      \
        pb1 = ((const float4*)brow1)[idx];                                      \
        pa0.x /= inA0; pa0.y /= inA0; pa0.z /= inA0; pa0.w /= inA0;             \
        pa1.x /= inA1; pa1.y /= inA1; pa1.z /= inA1; pa1.w /= inA1;             \
        pb0.x /= inB0; pb0.y /= inB0; pb0.z /= inB0; pb0.w /= inB0;             \
        pb1.x /= inB1; pb1.y /= inB1; pb1.z /= inB1; pb1.w /= inB1;             \
    } while (0)
#define WRITETILE(BUF)                                                          \
    do {                                                                        \
        *(float4*)&AsF[((BUF) * 64 + r0) * 36 + 4 * sl] = pa0;                  \
        *(float4*)&AsF[((BUF) * 64 + r0 + 32) * 36 + 4 * sl] = pa1;             \
        BsF[((BUF) * 32 + 4 * sl + 0) * 68 + r0] = pb0.x;                       \
        BsF[((BUF) * 32 + 4 * sl + 1) * 68 + r0] = pb0.y;                       \
        BsF[((BUF) * 32 + 4 * sl + 2) * 68 + r0] = pb0.z;                       \
        BsF[((BUF) * 32 + 4 * sl + 3) * 68 + r0] = pb0.w;                       \
        BsF[((BUF) * 32 + 4 * sl + 0) * 68 + r0 + 32] = pb1.x;                  \
        BsF[((BUF) * 32 + 4 * sl + 1) * 68 + r0 + 32] = pb1.y;                  \
        BsF[((BUF) * 32 + 4 * sl + 2) * 68 + r0 + 32] = pb1.z;                  \
        BsF[((BUF) * 32 + 4 * sl + 3) * 68 + r0 + 32] = pb1.w;                  \
    } while (0)
    LOADDIV(0);
    WRITETILE(0);
    LOADDIV(1);
    __syncthreads();                       // buf0 ready
    for (int s = 0; s < 24; s++) {
        int cur = s & 1;
        if (s + 1 < 24) WRITETILE(cur ^ 1);            // stage next (regs from s+1 load)
        if (s + 2 < 24) LOADDIV(s + 2);                // prefetch 2 ahead
#pragma unroll
        for (int c4 = 0; c4 < 8; c4++) {               // k = 32s + 4*c4 + kk, ascending
            float4 av[4], bk4[4];
#pragma unroll
            for (int a = 0; a < 4; a++)
                av[a] = *(const float4*)&AsF[(cur * 64 + ti * 4 + a) * 36 + 4 * c4];
#pragma unroll
            for (int k = 0; k < 4; k++)
                bk4[k] = *(const float4*)&BsF[(cur * 32 + 4 * c4 + k) * 68 + 4 * tj];
#pragma unroll
            for (int k = 0; k < 4; k++) {
#pragma unroll
                for (int a = 0; a < 4; a++) {
                    float ak = ((const float*)&av[a])[k];
#pragma unroll
                    for (int c = 0; c < 4; c++)
                        acc[a][c] += ak * ((const float*)&bk4[k])[c];
                }
            }
        }
        __syncthreads();                   // one barrier per step
    }
    // pack (sim, smaller-j-wins) into sortable u64; per-thread best over 4 cols
#pragma unroll
    for (int a = 0; a < 4; a++) {
        unsigned long long bp = 0ULL;
#pragma unroll
        for (int c = 0; c < 4; c++) {
            int jg = j0 + tj * 4 + c;
            unsigned u = __float_as_uint(acc[a][c]);
            u = (u & 0x80000000u) ? ~u : (u | 0x80000000u);
            unsigned long long pk = ((unsigned long long)u << 32) | (unsigned long long)(255 - jg);
            if (pk > bp) bp = pk;
        }
        cand[(ti * 4 + a) * 16 + tj] = bp;
    }
    __syncthreads();
    if (t < 64) {
        unsigned long long m = cand[t * 16];
#pragma unroll
        for (int c2 = 1; c2 < 16; c2++) { unsigned long long v = cand[t * 16 + c2]; if (v > m) m = v; }
        g_nodep_part[((size_t)b * HALF + i0 + t) * 4 + jt] = m;
    }
#undef LOADDIV
#undef WRITETILE
}

// ---------------- K_seledge: sel blocks 0..15 + W2 blocks 16..111 -----------
__global__ void k_seledge(const float* __restrict__ Wk, const float* __restrict__ bk) {
    int blk = blockIdx.x, t = threadIdx.x;
    __shared__ float v[LL];
    __shared__ int pos[LL];
    __shared__ float nm[HALF];
    __shared__ int   ni[HALF];
    __shared__ __align__(16) float qsl[HD];

    if (blk >= BB) {
        // ---- W2[b][h][d] = Wk_h[d,:] . q_h  (per-d order identical) --------
        int wb = blk - BB;
        int b = wb / NH2, h = wb % NH2;
        if (t < HD) qsl[t] = g_q[b * UDIM + h * HD + t];
        __syncthreads();
        if (t < 384) {
#pragma unroll
            for (int rep = 0; rep < 2; rep++) {
                int d = t + rep * 384;
                const float4* wrow = (const float4*)(Wk + (size_t)d * UDIM + h * HD);
                const float4* q4 = (const float4*)qsl;
                float4 s4 = {0.f, 0.f, 0.f, 0.f};
#pragma unroll
                for (int u4 = 0; u4 < 16; u4++) {
                    float4 w = wrow[u4], q = q4[u4];
                    s4.x += q.x * w.x; s4.y += q.y * w.y; s4.z += q.z * w.z; s4.w += q.w * w.w;
                }
                g_w2[((size_t)b * NH2 + h) * DD + d] = (s4.x + s4.y) + (s4.z + s4.w);
            }
        }
        if (t == 0) {
            float a = 0.f;
            for (int u = 0; u < HD; u++) a += qsl[u] * bk[h * HD + u];
            g_qbk[b * NH2 + h] = a;
        }
        return;
    }

    int b = blk;
    float imp = 0.f;
    for (int p = 0; p < NHEAD * 4; p++)
        imp += g_colsum_part[((size_t)b * NHEAD * 4 + p) * LL + t];
    v[t] = imp;
    __syncthreads();
    int cnt = 0;
    for (int k = 0; k < LL; k++) {
        float vk = v[k];
        cnt += (vk > imp) || (vk == imp && k < t);
    }
    int notp = (cnt >= KPRES) ? 1 : 0;
    pos[t] = notp;
    __syncthreads();
    for (int s = 1; s < LL; s <<= 1) {
        int add = (t >= s) ? pos[t - s] : 0;
        __syncthreads();
        pos[t] += add;
        __syncthreads();
    }
    if (notp) g_unp[b * RCNT + pos[t] - 1] = t;
    if (t < HALF) {
        unsigned long long p = g_nodep_part[((size_t)b * HALF + t) * 4 + 0];
#pragma unroll
        for (int q = 1; q < 4; q++) {
            unsigned long long w = g_nodep_part[((size_t)b * HALF + t) * 4 + q];
            if (w > p) p = w;
        }
        unsigned u = (unsigned)(p >> 32);
        unsigned bits = (u & 0x80000000u) ? (u & 0x7FFFFFFFu) : ~u;
        nm[t] = __uint_as_float(bits);
        ni[t] = 255 - (int)(p & 0xFFFFFFFFu);
    }
    __syncthreads();
    if (t < HALF) {
        float vv = nm[t];
        int cnt2 = 0;
        for (int k = 0; k < HALF; k++) {
            float vk = nm[k];
            cnt2 += (vk > vv) || (vk == vv && k < t);
        }
        if (cnt2 < RCNT) {
            g_srctok[b * RCNT + cnt2] = t;
            g_srcdst[b * RCNT + cnt2] = ni[t];
        } else {
            g_unm[b * RCNT + (cnt2 - RCNT)] = 2 * t;
        }
    }
}

// ---------------- K_attn: per-(b,h) attn chain (blocks 0..95) ---------------
// ----------------        + output rows 0..384 (blocks 96..)    --------------
__global__ void k_attn(const float* __restrict__ hs,
                       const float* __restrict__ Wv, const float* __restrict__ bv,
                       float* __restrict__ out) {
    int blk = blockIdx.x;
    int t = threadIdx.x;
    __shared__ __align__(16) float w2s[DD];
    __shared__ __align__(16) float hbars[DD];
    __shared__ int   toks[RCNT];
    __shared__ float att[RCNT];
    __shared__ float red[256];
    __shared__ float pm[4];
    __shared__ float qbkS;
    __shared__ int ss[RCNT], sd[RCNT];

    if (blk < BB * NH2) {
        int b = blk / NH2, h = blk % NH2;
        const float* hb = hs + (size_t)b * LL * DD;
        if (t < RCNT) toks[t] = g_unp[b * RCNT + t];
        for (int d = t; d < DD; d += 256) w2s[d] = g_w2[((size_t)b * NH2 + h) * DD + d];
        if (t == 0) qbkS = g_qbk[b * NH2 + h];
        __syncthreads();
        // --- logits: 2 threads per token, half a row each ---
        {
            int tok = t >> 1, half = t & 1;
            const float4* hr4 = (const float4*)(hb + (size_t)toks[tok] * DD) + half * 96;
            const float4* wk4 = (const float4*)w2s + half * 96;
            float4 s4 = {0.f, 0.f, 0.f, 0.f};
            for (int d4 = 0; d4 < 96; d4++) {
                float4 w = wk4[d4], x = hr4[d4];
                s4.x += w.x * x.x; s4.y += w.y * x.y; s4.z += w.z * x.z; s4.w += w.w * x.w;
            }
            red[t] = (s4.x + s4.y) + (s4.z + s4.w);
        }
        __syncthreads();
        float lg = -1e30f;
        if (t < RCNT) lg = (qbkS + red[2 * t] + red[2 * t + 1]) * 0.125f;
        // --- softmax ---
        float m = lg;
#pragma unroll
        for (int off = 32; off >= 1; off >>= 1) m = fmaxf(m, __shfl_xor(m, off, 64));
        if ((t & 63) == 0) pm[t >> 6] = m;
        __syncthreads();
        float mx = fmaxf(pm[0], pm[1]);
        float e = (t < RCNT) ? expf(lg - mx) : 0.f;
        float sume = e;
#pragma unroll
        for (int off = 32; off >= 1; off >>= 1) sume += __shfl_xor(sume, off, 64);
        __syncthreads();
        if ((t & 63) == 0) pm[t >> 6] = sume;
        __syncthreads();
        float inv = 1.f / (pm[0] + pm[1]);
        if (t < RCNT) att[t] = e * inv;
        __syncthreads();
        // --- hbar = sum_tok att * H_tok (ascending tok) ---
        if (t < DD / 4) {
            float4 a = {0.f, 0.f, 0.f, 0.f};
            for (int s2 = 0; s2 < RCNT; s2++) {
                float4 x = ((const float4*)(hb + (size_t)toks[s2] * DD))[t];
                float w = att[s2];
                a.x += w * x.x; a.y += w * x.y; a.z += w * x.z; a.w += w * x.w;
            }
            *(float4*)&hbars[4 * t] = a;
        }
        __syncthreads();
        // --- ctx = hbar @ Wv_h + bv (4 partials of 192) ---
        {
            int u = t & 63, part = t >> 6;
            float a = 0.f;
            for (int d = part * 192; d < part * 192 + 192; d++)
                a += hbars[d] * Wv[(size_t)d * UDIM + h * HD + u];
            red[t] = a;
            __syncthreads();
            if (t < HD)
                g_ctx[b * UDIM + h * HD + t] =
                    bv[h * HD + t] + red[t] + red[t + 64] + red[t + 128] + red[t + 192];
        }
        return;
    }

    // ================= output rows 0..384 (copy / unm / merge) ==============
    int rblk = blk - BB * NH2;
    int row = rblk % 385, b = rblk / 385;
    float4* o4 = (float4*)(out + ((size_t)b * 386 + row) * DD);
    if (row == 0) {
        if (t < 192) {
            const float4* s4 = (const float4*)(hs + (size_t)b * LL * DD);
            o4[t] = s4[t];
        }
    } else if (row <= RCNT) {
        int tok = g_unm[b * RCNT + row - 1];
        if (t < 192) {
            const float4* s4 = (const float4*)(hs + ((size_t)b * LL + tok) * DD);
            o4[t] = s4[t];
        }
    } else {
        int j = row - 1 - RCNT;
        if (t < RCNT) { ss[t] = g_srctok[b * RCNT + t]; sd[t] = g_srcdst[b * RCNT + t]; }
        __syncthreads();
        if (t < 192) {
            float4 acc = ((const float4*)(hs + ((size_t)b * LL + 2 * j + 1) * DD))[t];
            float cnt = 1.f;
            for (int s2 = 0; s2 < RCNT; s2++) {   // ascending rank == np.add.at order
                if (sd[s2] == j) {
                    float4 v = ((const float4*)(hs + ((size_t)b * LL + 2 * ss[s2]) * DD))[t];
                    acc.x += v.x; acc.y += v.y; acc.z += v.z; acc.w += v.w;
                    cnt += 1.f;
                }
            }
            float4 r;
            r.x = acc.x / cnt; r.y = acc.y / cnt; r.z = acc.z / cnt; r.w = acc.w / cnt;
            o4[t] = r;
        }
    }
}

// ---------------- K_newtok: row 385 per batch, 4 blocks/batch ---------------
__global__ void k_newtok(const float* __restrict__ Wo, const float* __restrict__ bo,
                         float* __restrict__ out) {
    int b = blockIdx.x >> 2, q = blockIdx.x & 3;
    int t = threadIdx.x;
    __shared__ float c[UDIM];
    c[t] = g_ctx[b * UDIM + t];
    c[t + 192] = g_ctx[b * UDIM + t + 192];
    __syncthreads();
    int dd = q * 192 + t;
    float acc = bo[dd];
    for (int u = 0; u < UDIM; u++)
        acc += c[u] * Wo[(size_t)u * DD + dd];
    out[((size_t)b * 386 + 385) * DD + dd] = acc;
}

extern "C" void kernel_launch(void* const* d_in, const int* in_sizes, int n_in,
                              void* d_out, int out_size, void* d_ws, size_t ws_size,
                              hipStream_t stream) {
    const float* hs = (const float*)d_in[0];
    const float* sc = (const float*)d_in[1];
    const float* Wq = (const float*)d_in[2];
    const float* bq = (const float*)d_in[3];
    const float* Wk = (const float*)d_in[4];
    const float* bk = (const float*)d_in[5];
    const float* Wv = (const float*)d_in[6];
    const float* bv = (const float*)d_in[7];
    const float* Wo = (const float*)d_in[8];
    const float* bo = (const float*)d_in[9];
    float* out = (float*)d_out;
    (void)d_ws; (void)ws_size;

    k_main<<<256 + BB * NHEAD * 4 + BB * NH2, 256, 0, stream>>>(sc, hs, Wq, bq);
    k_seledge<<<BB + BB * NH2, 512, 0, stream>>>(Wk, bk);
    k_attn<<<BB * NH2 + BB * 385, 256, 0, stream>>>(hs, Wv, bv, out);
    k_newtok<<<BB * 4, 192, 0, stream>>>(Wo, bo, out);
}